// Round 8
// baseline (23688.387 us; speedup 1.0000x reference)
//
#include <hip/hip_runtime.h>
#include <cstddef>

#define B_DIM 32
#define T_DIM 1000
#define I_DIM 3
#define R_DIM 2048
#define O_DIM 3
#define NBLK 256
#define ROWS 8          // reservoir rows per block
#define NTHR 1024       // 16 waves: wave-group q = wv>>2 owns k-quarter q
#define KCH 128         // k per chunk (lane*2 within chunk)
#define NCH 4           // chunks per quarter (4*128 = 512)

// Persistent kernel, round 8.
// vs round 7 (18.5ms, VALUBusy 20%, Occupancy 25% = 2 waves/SIMD,
// latency-starved on LLC round-trips for fresh state lines):
//   - 1024 threads/block (16 waves/CU, 4/SIMD): k split in 4 quarters,
//     per-thread FMAs halve, latency hiding doubles twice.
//   - register structure identical per thread (acc[64] + 2-deep float2
//     staging); launch_bounds(1024,1) keeps the same 128-VGPR cap that
//     compiled spill-free in round 7.
//   - barrier, sc1-store ordering, readout: unchanged (verified 2 rounds).
__global__ __launch_bounds__(NTHR, 1) void esn_persist(
    const float* __restrict__ x,      // [B][T][I]
    const float* __restrict__ Win,    // [R][I]
    const float* __restrict__ Wres,   // [R][R]
    const float* __restrict__ Wout,   // [O][R]
    const float* __restrict__ noise,  // [B][R]
    float* __restrict__ states,       // [B][T][R]
    float* __restrict__ out,          // [B][O]
    int* __restrict__ flags)          // [NBLK] in ws (poison 0xAA = negative)
{
  __shared__ float cross[3][4][64];   // quarter-combine (3 KB)

  const int tid   = threadIdx.x;
  const int blk   = blockIdx.x;
  const int r0    = blk * ROWS;
  const int wv    = tid >> 6;         // wave 0..15
  const int q     = wv >> 2;          // k-quarter 0..3
  const int wv4   = wv & 3;           // batch-group
  const int lane  = tid & 63;
  const int bbase = wv4 * 8;

  // output mapping: lane L -> (batch = bbase + (L>>3), row = r0 + (L&7))
  // -> 8 consecutive lanes store 32 contiguous bytes.
  const int ob  = bbase + (lane >> 3);
  const int orr = r0 + (lane & 7);

  // t-invariant ext-term pieces (q==0 lanes produce outputs)
  float w0 = 0.f, w1 = 0.f, w2 = 0.f, nz = 0.f;
  if (q == 0) {
    w0 = Win[orr * I_DIM + 0];
    w1 = Win[orr * I_DIM + 1];
    w2 = Win[orr * I_DIM + 2];
    nz = noise[(size_t)ob * R_DIM + orr];
  }

  // per-lane k base within this quarter; per-row/batch base pointers
  const int klb = q * 512 + lane * 2;
  const float* wp[8];
  const float* sp0[8];
#pragma unroll
  for (int r = 0; r < 8; ++r) wp[r] = Wres + (size_t)(r0 + r) * R_DIM + klb;
#pragma unroll
  for (int j = 0; j < 8; ++j)
    sp0[j] = states + (size_t)(bbase + j) * T_DIM * R_DIM + klb;

#define LOADC(kc, SF, WF)                                                      \
  {                                                                            \
    _Pragma("unroll")                                                          \
    for (int j = 0; j < 8; ++j)                                                \
      SF[j] = *(const float2*)(sp0[j] + soff + (kc) * KCH);                    \
    _Pragma("unroll")                                                          \
    for (int r = 0; r < 8; ++r)                                                \
      WF[r] = *(const float2*)(wp[r] + (kc) * KCH);                            \
  }

#define FMAC(SF, WF)                                                           \
  {                                                                            \
    _Pragma("unroll")                                                          \
    for (int j = 0; j < 8; ++j) {                                              \
      _Pragma("unroll")                                                        \
      for (int r = 0; r < 8; ++r)                                              \
        acc[j * 8 + r] += WF[r].x * SF[j].x + WF[r].y * SF[j].y;               \
    }                                                                          \
  }

#pragma unroll 1
  for (int t = 0; t < T_DIM; ++t) {
    // per-step input loads issued early (latency hides under the k-loop)
    float x0 = 0.f, x1 = 0.f, x2 = 0.f;
    if (q == 0) {
      const float* xp = &x[((size_t)ob * T_DIM + t) * I_DIM];
      x0 = xp[0]; x1 = xp[1]; x2 = xp[2];
    }

    float acc[64];
#pragma unroll
    for (int i = 0; i < 64; ++i) acc[i] = 0.f;

    if (t > 0) {
      const size_t soff = (size_t)(t - 1) * R_DIM;
      float2 sA[8], wA[8], sB[8], wB[8];
      LOADC(0, sA, wA);
#pragma unroll
      for (int kc = 0; kc < NCH; kc += 2) {
        LOADC(kc + 1, sB, wB);              // prefetch odd chunk
        FMAC(sA, wA);                       // compute even chunk
        if (kc + 2 < NCH) LOADC(kc + 2, sA, wA);
        FMAC(sB, wB);                       // compute odd chunk
      }
    }

    // ---- in-place keep-half butterfly: acc[0] = lane L's partial for its k-quarter
#pragma unroll
    for (int m = 32; m >= 1; m >>= 1) {
#pragma unroll
      for (int i = 0; i < m; ++i) {
        const bool hh = (lane & m) != 0;
        const float mine = hh ? acc[i] : acc[i + m];
        const float keep = hh ? acc[i + m] : acc[i];
        acc[i] = keep + __shfl_xor(mine, m, 64);
      }
    }

    // ---- combine k-quarters, activation, sc1 store (LLC-visible)
    if (q > 0) cross[q - 1][wv4][lane] = acc[0];
    __syncthreads();
    if (q == 0) {
      const float tot = acc[0] + cross[0][wv4][lane] + cross[1][wv4][lane] +
                        cross[2][wv4][lane];
      const float val = tanhf(x0 * w0 + x1 * w1 + x2 * w2 + nz + tot);
      __hip_atomic_store(&states[((size_t)ob * T_DIM + t) * R_DIM + orr], val,
                         __ATOMIC_RELAXED, __HIP_MEMORY_SCOPE_AGENT);
    }
    // barrier's built-in s_waitcnt vmcnt(0) retires every wave's sc1 stores
    // at the LLC before any wave proceeds -> release ordering without wbl2.
    __syncthreads();

    // ---- grid barrier: RELAXED flag release + spin on all 256 flags
    if (tid == 0)
      __hip_atomic_store(&flags[blk], t + 1, __ATOMIC_RELAXED,
                         __HIP_MEMORY_SCOPE_AGENT);
    if (wv == 0 && (t + 1 < T_DIM || blk == 0)) {
      const int target = t + 1;
      int guard = 0;
      for (;;) {
        const int v0 = __hip_atomic_load(&flags[lane], __ATOMIC_RELAXED,
                                         __HIP_MEMORY_SCOPE_AGENT);
        const int v1 = __hip_atomic_load(&flags[lane + 64], __ATOMIC_RELAXED,
                                         __HIP_MEMORY_SCOPE_AGENT);
        const int v2 = __hip_atomic_load(&flags[lane + 128], __ATOMIC_RELAXED,
                                         __HIP_MEMORY_SCOPE_AGENT);
        const int v3 = __hip_atomic_load(&flags[lane + 192], __ATOMIC_RELAXED,
                                         __HIP_MEMORY_SCOPE_AGENT);
        const bool ok =
            (v0 >= target) && (v1 >= target) && (v2 >= target) && (v3 >= target);
        if (__all(ok)) break;
        if (++guard > (1 << 22)) break;  // deadlock escape (never in practice)
        __builtin_amdgcn_s_sleep(1);
      }
    }
    __builtin_amdgcn_fence(__ATOMIC_ACQUIRE, "workgroup");  // compiler fence
    __syncthreads();
  }

  // ---- readout: outputs[b][o] = states[b][T-1][:] . Wout[o][:]
  if (blk == 0) {
#pragma unroll 1
    for (int pi = 0; pi < 6; ++pi) {
      const int p = wv * 6 + pi;       // 16 waves x 6 = 96 pairs
      const int b = p / 3, o = p % 3;
      const float* sp = &states[((size_t)b * T_DIM + (T_DIM - 1)) * R_DIM];
      const float* wq = &Wout[(size_t)o * R_DIM];
      float a = 0.f;
#pragma unroll
      for (int j = 0; j < 8; ++j) {
        const int rr = j * 256 + lane * 4;
        const float4 s = *(const float4*)&sp[rr];
        const float4 w = *(const float4*)&wq[rr];
        a += s.x * w.x + s.y * w.y + s.z * w.z + s.w * w.w;
      }
#pragma unroll
      for (int m = 32; m >= 1; m >>= 1) a += __shfl_xor(a, m, 64);
      if (lane == 0) out[(size_t)b * O_DIM + o] = a;
    }
  }
}

extern "C" void kernel_launch(void* const* d_in, const int* in_sizes, int n_in,
                              void* d_out, int out_size, void* d_ws, size_t ws_size,
                              hipStream_t stream) {
  const float* x     = (const float*)d_in[0];
  const float* Win   = (const float*)d_in[1];
  const float* Wres  = (const float*)d_in[2];
  const float* Wout  = (const float*)d_in[3];
  const float* noise = (const float*)d_in[4];

  float* out    = (float*)d_out;              // [32,3]
  float* states = out + B_DIM * O_DIM;        // [32,1000,2048]
  int* flags    = (int*)d_ws;                 // [256], poison 0xAA < 1 (signed)

  esn_persist<<<NBLK, NTHR, 0, stream>>>(x, Win, Wres, Wout, noise,
                                         states, out, flags);
}